// Round 10
// baseline (249.417 us; speedup 1.0000x reference)
//
#include <hip/hip_runtime.h>
#include <hip/hip_fp16.h>
#include <math.h>

#define LRELU_ALPHA 0.2f
#define NEG_INF -1000000000.0f
#define L2E 1.44269504088896340736f  // log2(e)

constexpr int B_ = 8, N_ = 2048, FIN = 128, FOUT = 64;

typedef _Float16 __attribute__((ext_vector_type(8))) f16x8;
typedef float __attribute__((ext_vector_type(4))) f32x4;

// async global->LDS, 16B per lane; wave-uniform LDS base (lane*16 added by HW)
__device__ __forceinline__ void gload16(const void* g, void* l) {
  __builtin_amdgcn_global_load_lds(
      (const __attribute__((address_space(1))) void*)g,
      (__attribute__((address_space(3))) void*)l, 16, 0, 0);
}

// ---------------------------------------------------------------------------
// Kernel 1 (unchanged, proven): Wh = h @ W^T (fp32), emitted as fp16
// transposed WhT[b][o][n]; also s1 = Wh@a1, s2 = Wh@a2 (fp32).
// ---------------------------------------------------------------------------
__global__ __launch_bounds__(256) void k_wh(
    const float* __restrict__ h, const float* __restrict__ W,
    const float* __restrict__ a, unsigned short* __restrict__ WhT,
    float* __restrict__ s1, float* __restrict__ s2) {
  __shared__ float Wt[128][65];  // [f][o]: read bank (f+o)%32 -> conflict-free
  __shared__ float hs[16][128];

  const int t = threadIdx.x;
  const int row0 = blockIdx.x * 16;

  for (int e = t; e < 64 * 128; e += 256) {
    int o = e >> 7, f = e & 127;
    Wt[f][o] = W[e];
  }
  {
    const float4* hg = (const float4*)(h + (size_t)row0 * FIN);
    for (int i4 = t; i4 < 16 * 32; i4 += 256) {
      int r = i4 >> 5, f4 = i4 & 31;
      *(float4*)&hs[r][f4 * 4] = hg[i4];
    }
  }
  __syncthreads();

  const int wave = t >> 6, lane = t & 63;  // lane = o
  float acc[4] = {0.f, 0.f, 0.f, 0.f};
#pragma unroll 4
  for (int f4 = 0; f4 < 32; ++f4) {
    float w0 = Wt[4 * f4 + 0][lane], w1 = Wt[4 * f4 + 1][lane];
    float w2 = Wt[4 * f4 + 2][lane], w3 = Wt[4 * f4 + 3][lane];
#pragma unroll
    for (int r = 0; r < 4; ++r) {
      float4 hv = *(const float4*)&hs[wave * 4 + r][f4 * 4];
      acc[r] += hv.x * w0 + hv.y * w1 + hv.z * w2 + hv.w * w3;
    }
  }

  const float a1v = a[lane], a2v = a[64 + lane];
  const int b = row0 / N_;
#pragma unroll
  for (int r = 0; r < 4; ++r) {
    const int row = row0 + wave * 4 + r;
    const int n = row - b * N_;
    const float v = acc[r];
    WhT[((size_t)b * 64 + lane) * N_ + n] = __half_as_ushort(__float2half(v));
    float p1 = v * a1v, p2 = v * a2v;
#pragma unroll
    for (int d = 32; d; d >>= 1) {
      p1 += __shfl_xor(p1, d, 64);
      p2 += __shfl_xor(p2, d, 64);
    }
    if (lane == 0) { s1[row] = p1; s2[row] = p2; }
  }
}

// ---------------------------------------------------------------------------
// Kernel 2 v9: fused sequential adj-pack + v3b mask-driven DMA pipeline.
// Block = 32 i-rows x 64 o, grid (N/32, B) = 512. Two phases:
// PHASE 1 (in-kernel pack): wave w reads adj rows i0+w*8..+8 FULLY
//   SEQUENTIALLY (8 KB runs, 8x int4 per row — the k_pack pattern that
//   streams at HBM rate, vs the 256B-per-row x16-row fragment order that
//   every earlier k_attn paid 2-3x for). __ballot packs each 1KB segment
//   into 4 u64: pkls[row][k*4+i] bit l = adj[row][k*256+4l+i] (bit math
//   identical to v8's VERIFIED k_pack/extract pair). LDS table padded
//   [32][34] (272B row stride: 16B-aligned, 2-way banks = free).
// PHASE 2: v3b's depth-3 counted-vmcnt loop, WhT only. Per chunk (64 j):
//   8 KB staged by 8 gload16 (wave w stages o-group w, slots (w*2+ks));
//   steady FV(4) = own chunk c landed, chunks c+1,c+2 (4 ops) in flight
//   across the barrier. Masks: 4 u64 read from LDS once per 4 chunks.
//   exp once per element; p = exp2(max(c1+x, 0.2x+c2)); ones-MFMA rowsum.
// All main-loop memory is XCD-L2-local (WhT 2MB, b = blockIdx.y pins batch
// pages hot); adj touched only in phase 1 at stream rate.
// ---------------------------------------------------------------------------
__global__ __launch_bounds__(256, 2) void k_attn(
    const unsigned short* __restrict__ WhT,
    const float* __restrict__ s1g, const float* __restrict__ s2g,
    const int* __restrict__ adj, float* __restrict__ out) {
  __shared__ __align__(16) unsigned char sbuf[4][8 * 1024];
  __shared__ unsigned long long pkls[32][34];  // +2 pad: align + bank spread
  __shared__ float s2s[N_];

  const int t = threadIdx.x;
  const int wave = t >> 6, lane = t & 63;
  const int m = lane & 15, q = lane >> 4;
  const int b = blockIdx.y;
  const int i0 = blockIdx.x * 32;
  const int rg = wave & 1;         // row-group (rows rg*16..+16)
  const int p0 = (wave >> 1) * 2;  // first o-group of this wave's pair

  const int* adjB = adj + (size_t)b * N_ * N_;
  const unsigned short* whB = WhT + (size_t)b * 64 * N_;

  // preload s2 row (8 KB), pre-scaled by log2(e)
  {
    const float4* s2R = (const float4*)(s2g + (size_t)b * N_);
    for (int i = t; i < N_ / 4; i += 256) {
      float4 v = s2R[i];
      v.x *= L2E; v.y *= L2E; v.z *= L2E; v.w *= L2E;
      ((float4*)s2s)[i] = v;
    }
  }

  // ---- PHASE 1: sequential pack of this block's 32 adj rows ----
  {
    const int4* asrc = (const int4*)(adjB + (size_t)(i0 + wave * 8) * N_);
    for (int r8 = 0; r8 < 8; ++r8) {
      const int4* rs = asrc + (size_t)r8 * (N_ / 4);
      unsigned long long* prow = &pkls[wave * 8 + r8][0];
#pragma unroll
      for (int k = 0; k < 8; ++k) {
        int4 v = rs[k * 64 + lane];
        unsigned long long b0 = __ballot(v.x != 0);
        unsigned long long b1 = __ballot(v.y != 0);
        unsigned long long b2 = __ballot(v.z != 0);
        unsigned long long b3 = __ballot(v.w != 0);
        unsigned long long sel = (lane == 0) ? b0
                               : (lane == 1) ? b1
                               : (lane == 2) ? b2 : b3;
        if (lane < 4) prow[k * 4 + lane] = sel;
      }
    }
  }

  const float s1r = s1g[b * N_ + i0 + rg * 16 + m];
  const float c1 = (s1r - 2.0f) * L2E;                // x-2 branch (base-2)
  const float c2 = (LRELU_ALPHA * s1r - 2.0f) * L2E;  // 0.2x-2 branch

  f16x8 ones;
#pragma unroll
  for (int j = 0; j < 8; ++j) ones[j] = (_Float16)1.0f;

  // WhT staging: wave stages o-group g=wave into slots (wave*2+ks)*1024.
  const unsigned short* whP0 = whB + (size_t)(wave * 16 + m) * N_ + q * 8;
  const unsigned short* whP1 = whP0 + 32;  // ks=1

#define STAGE(S, c)                                           \
  {                                                           \
    gload16(whP0 + (c) * 64, (S) + (wave * 2 + 0) * 1024);    \
    gload16(whP1 + (c) * 64, (S) + (wave * 2 + 1) * 1024);    \
  }
// mask extraction (v8-verified): for chunk c, ks: l0 = (c&3)*16+ks*8+q*2;
// bit for j: ((u32)(mk[j&3] >> l0) >> (j>>2)) & 1
#define CONSUME(BASE, c)                                                     \
  {                                                                          \
    _Pragma("unroll") for (int ks = 0; ks < 2; ++ks) {                       \
      const unsigned l0 =                                                    \
          ((unsigned)((c)&3)) * 16u + (unsigned)ks * 8u + (unsigned)q * 2u;  \
      const unsigned w0 = (unsigned)(mk01.x >> l0);                          \
      const unsigned w1 = (unsigned)(mk01.y >> l0);                          \
      const unsigned w2 = (unsigned)(mk23.x >> l0);                          \
      const unsigned w3 = (unsigned)(mk23.y >> l0);                          \
      const float* sp = &s2s[(c) * 64 + ks * 32 + q * 8];                    \
      float4 sv0 = *(const float4*)sp;                                       \
      float4 sv1 = *(const float4*)(sp + 4);                                 \
      float xs[8] = {sv0.x, sv0.y, sv0.z, sv0.w, sv1.x, sv1.y, sv1.z, sv1.w};\
      f16x8 af;                                                              \
      _Pragma("unroll") for (int j = 0; j < 8; ++j) {                        \
        float x = xs[j];                                                     \
        float e = fmaxf(c1 + x, fmaf(LRELU_ALPHA, x, c2));                   \
        const unsigned sel = ((j & 3) == 0) ? w0                             \
                           : ((j & 3) == 1) ? w1                             \
                           : ((j & 3) == 2) ? w2 : w3;                       \
        e = ((sel >> (j >> 2)) & 1u) ? e : NEG_INF;                          \
        af[j] = (_Float16)__builtin_amdgcn_exp2f(e);  /* masked -> 0 */      \
      }                                                                      \
      f16x8 b0 =                                                             \
          *(const f16x8*)((BASE) + ((p0 + 0) * 2 + ks) * 1024 + lane * 16);  \
      f16x8 b1 =                                                             \
          *(const f16x8*)((BASE) + ((p0 + 1) * 2 + ks) * 1024 + lane * 16);  \
      acc0 = __builtin_amdgcn_mfma_f32_16x16x32_f16(af, b0, acc0, 0, 0, 0);  \
      acc1 = __builtin_amdgcn_mfma_f32_16x16x32_f16(af, b1, acc1, 0, 0, 0);  \
      accS = __builtin_amdgcn_mfma_f32_16x16x32_f16(af, ones, accS, 0, 0, 0);\
    }                                                                        \
  }
#define FV(NN) asm volatile("s_waitcnt vmcnt(" #NN ")" ::: "memory");
#define BAR() __builtin_amdgcn_s_barrier();

  f32x4 acc0 = {0.f, 0.f, 0.f, 0.f}, acc1 = acc0, accS = acc0;
  const unsigned long long* mrow = &pkls[rg * 16 + m][0];

  // prologue: chunks 0..2 staged; one full drain (publishes s2s + pkls too)
  STAGE(sbuf[0], 0)
  STAGE(sbuf[1], 1)
  STAGE(sbuf[2], 2)
  __syncthreads();

  for (int g = 0; g < 7; ++g) {
    ulonglong2 mk01 = *(const ulonglong2*)(mrow + g * 4);
    ulonglong2 mk23 = *(const ulonglong2*)(mrow + g * 4 + 2);
    const int c = 4 * g;
    FV(4) BAR() CONSUME(sbuf[0], c + 0) STAGE(sbuf[3], c + 3)
    FV(4) BAR() CONSUME(sbuf[1], c + 1) STAGE(sbuf[0], c + 4)
    FV(4) BAR() CONSUME(sbuf[2], c + 2) STAGE(sbuf[1], c + 5)
    FV(4) BAR() CONSUME(sbuf[3], c + 3) STAGE(sbuf[2], c + 6)
  }
  {  // tail group g=7: chunks 28..31; last STAGE is chunk 31
    ulonglong2 mk01 = *(const ulonglong2*)(mrow + 28);
    ulonglong2 mk23 = *(const ulonglong2*)(mrow + 30);
    FV(4) BAR() CONSUME(sbuf[0], 28) STAGE(sbuf[3], 31)
    FV(4) BAR() CONSUME(sbuf[1], 29)
    FV(2) BAR() CONSUME(sbuf[2], 30)
    FV(0) BAR() CONSUME(sbuf[3], 31)
  }

  // C/D layout: row_in_tile = q*4 + r, col = m; accS[r] = rowsum(q*4+r)
#pragma unroll
  for (int r = 0; r < 4; ++r) {
    const int ri = q * 4 + r;
    const float l = accS[r];
    const float inv = (l == 0.f) ? 1.f : 1.f / l;  // fully-masked row guard
    const size_t row = (size_t)b * N_ + i0 + rg * 16 + ri;
    out[row * FOUT + (p0 + 0) * 16 + m] = acc0[r] * inv;
    out[row * FOUT + (p0 + 1) * 16 + m] = acc1[r] * inv;
  }
#undef STAGE
#undef CONSUME
#undef FV
#undef BAR
}

extern "C" void kernel_launch(void* const* d_in, const int* in_sizes, int n_in,
                              void* d_out, int out_size, void* d_ws, size_t ws_size,
                              hipStream_t stream) {
  const float* h   = (const float*)d_in[0];
  const int*   adj = (const int*)d_in[1];
  const float* W   = (const float*)d_in[2];
  const float* a   = (const float*)d_in[3];
  float* out = (float*)d_out;

  // ws: WhT fp16 (2 MB) | s1 (64 KB) | s2 (64 KB)
  unsigned short* WhT = (unsigned short*)d_ws;
  float* s1 = (float*)(WhT + (size_t)B_ * 64 * N_);
  float* s2 = s1 + (size_t)B_ * N_;

  k_wh<<<dim3(B_ * N_ / 16), 256, 0, stream>>>(h, W, a, WhT, s1, s2);
  k_attn<<<dim3(N_ / 32, B_), 256, 0, stream>>>(WhT, s1, s2, adj, out);
}

// Round 11
// 225.323 us; speedup vs baseline: 1.1069x; 1.1069x over previous
//
#include <hip/hip_runtime.h>
#include <hip/hip_fp16.h>
#include <math.h>

#define LRELU_ALPHA 0.2f
#define NEG_INF -1000000000.0f
#define L2E 1.44269504088896340736f  // log2(e)

constexpr int B_ = 8, N_ = 2048, FIN = 128, FOUT = 64;

typedef _Float16 __attribute__((ext_vector_type(8))) f16x8;
typedef float __attribute__((ext_vector_type(4))) f32x4;

// async global->LDS, 16B per lane; lane l's data lands at ldsbase + l*16
__device__ __forceinline__ void gload16(const void* g, void* l) {
  __builtin_amdgcn_global_load_lds(
      (const __attribute__((address_space(1))) void*)g,
      (__attribute__((address_space(3))) void*)l, 16, 0, 0);
}

// ---------------------------------------------------------------------------
// Kernel 1 (unchanged, proven): Wh = h @ W^T (fp32), emitted as fp16
// transposed WhT[b][o][n]; also s1 = Wh@a1, s2 = Wh@a2 (fp32).
// ---------------------------------------------------------------------------
__global__ __launch_bounds__(256) void k_wh(
    const float* __restrict__ h, const float* __restrict__ W,
    const float* __restrict__ a, unsigned short* __restrict__ WhT,
    float* __restrict__ s1, float* __restrict__ s2) {
  __shared__ float Wt[128][65];  // [f][o]: read bank (f+o)%32 -> conflict-free
  __shared__ float hs[16][128];

  const int t = threadIdx.x;
  const int row0 = blockIdx.x * 16;

  for (int e = t; e < 64 * 128; e += 256) {
    int o = e >> 7, f = e & 127;
    Wt[f][o] = W[e];
  }
  {
    const float4* hg = (const float4*)(h + (size_t)row0 * FIN);
    for (int i4 = t; i4 < 16 * 32; i4 += 256) {
      int r = i4 >> 5, f4 = i4 & 31;
      *(float4*)&hs[r][f4 * 4] = hg[i4];
    }
  }
  __syncthreads();

  const int wave = t >> 6, lane = t & 63;  // lane = o
  float acc[4] = {0.f, 0.f, 0.f, 0.f};
#pragma unroll 4
  for (int f4 = 0; f4 < 32; ++f4) {
    float w0 = Wt[4 * f4 + 0][lane], w1 = Wt[4 * f4 + 1][lane];
    float w2 = Wt[4 * f4 + 2][lane], w3 = Wt[4 * f4 + 3][lane];
#pragma unroll
    for (int r = 0; r < 4; ++r) {
      float4 hv = *(const float4*)&hs[wave * 4 + r][f4 * 4];
      acc[r] += hv.x * w0 + hv.y * w1 + hv.z * w2 + hv.w * w3;
    }
  }

  const float a1v = a[lane], a2v = a[64 + lane];
  const int b = row0 / N_;
#pragma unroll
  for (int r = 0; r < 4; ++r) {
    const int row = row0 + wave * 4 + r;
    const int n = row - b * N_;
    const float v = acc[r];
    WhT[((size_t)b * 64 + lane) * N_ + n] = __half_as_ushort(__float2half(v));
    float p1 = v * a1v, p2 = v * a2v;
#pragma unroll
    for (int d = 32; d; d >>= 1) {
      p1 += __shfl_xor(p1, d, 64);
      p2 += __shfl_xor(p2, d, 64);
    }
    if (lane == 0) { s1[row] = p1; s2[row] = p2; }
  }
}

// ---------------------------------------------------------------------------
// Kernel 2 v10: v3b VERBATIM except the grid is transposed to (B, N/32) so
// linear block id = b + 8*iblk -> XCD = linear%8 = b: all 64 blocks of batch
// b run on XCD b (64 blocks / 32 CUs = 2/CU, balanced). Each XCD's private
// L2 then holds exactly ONE batch's WhT (256 KB) + s2 row (8 KB), making
// the 134 MB of chip-wide WhT re-reads L2-local instead of fabric traffic.
// Ten-round traffic model: every variant's k_attn time ~= total bytes moved
// (adj once + WhT x re-reads) / ~4.8 TB/s effective -> cutting WhT re-read
// traffic to near-zero leaves the adj stream (134 MB, ~21 us) as the floor.
// Pipeline (proven in r3): 4 LDS bufs, stage 3 ahead, counted vmcnt(8)
// before each barrier (chunks c+1,c+2 stay in flight), 1 barrier/chunk.
// Row sums via ones-MFMA; exp in base-2 with folded constants.
// ---------------------------------------------------------------------------
__global__ __launch_bounds__(256, 2) void k_attn(
    const unsigned short* __restrict__ WhT,
    const float* __restrict__ s1g, const float* __restrict__ s2g,
    const int* __restrict__ adj, float* __restrict__ out) {
  __shared__ __align__(16) unsigned char sbuf[4][16 * 1024];
  __shared__ float s2s[N_];

  const int t = threadIdx.x;
  const int wave = t >> 6, lane = t & 63;
  const int m = lane & 15, q = lane >> 4;
  const int b = blockIdx.x;        // fastest dim -> XCD = b (8 XCDs)
  const int i0 = blockIdx.y * 32;
  const int rg = wave & 1;         // row-group (rows rg*16..+16)
  const int p0 = (wave >> 1) * 2;  // first o-group of this wave's pair

  const int* adjB = adj + (size_t)b * N_ * N_;
  const unsigned short* whB = WhT + (size_t)b * 64 * N_;

  // preload s2 row (8 KB), pre-scaled by log2(e)
  {
    const float4* s2R = (const float4*)(s2g + (size_t)b * N_);
    for (int i = t; i < N_ / 4; i += 256) {
      float4 v = s2R[i];
      v.x *= L2E; v.y *= L2E; v.z *= L2E; v.w *= L2E;
      ((float4*)s2s)[i] = v;
    }
  }

  const float s1r = s1g[b * N_ + i0 + rg * 16 + m];
  const float c1 = (s1r - 2.0f) * L2E;                // x-2 branch (base-2)
  const float c2 = (LRELU_ALPHA * s1r - 2.0f) * L2E;  // 0.2x-2 branch

  f16x8 ones;
#pragma unroll
  for (int j = 0; j < 8; ++j) ones[j] = (_Float16)1.0f;

  // per-wave staging sources (4 DMA instrs per wave per chunk):
  //  waves 0,1: adj rows rg*16..+16, instr ii -> (ks=ii>>1, h=ii&1)
  //  waves 2,3: WhT,               instr ii -> (g=(w-2)*2+(ii>>1), ks=ii&1)
  // LDS slot layout: instr idx*1024 + lane*16, where
  //  adj idx = rg*4 + ks*2 + h ; WhT idx = 8 + g*2 + ks
  const unsigned char* gp[4];
  int gstr;
  if (wave < 2) {
    const size_t r = (size_t)(i0 + wave * 16 + m);
#pragma unroll
    for (int ii = 0; ii < 4; ++ii) {
      int ks = ii >> 1, hh = ii & 1;
      gp[ii] = (const unsigned char*)(adjB + r * N_ + ks * 32 + q * 8 + hh * 4);
    }
    gstr = 64 * 4;   // 64 ints per chunk
  } else {
#pragma unroll
    for (int ii = 0; ii < 4; ++ii) {
      int g = (wave - 2) * 2 + (ii >> 1), ks = ii & 1;
      gp[ii] = (const unsigned char*)(whB + (size_t)(g * 16 + m) * N_ +
                                      ks * 32 + q * 8);
    }
    gstr = 64 * 2;   // 64 fp16 per chunk
  }

#define STAGE(S, c)                                                       \
  {                                                                       \
    _Pragma("unroll") for (int ii = 0; ii < 4; ++ii)                      \
        gload16(gp[ii] + (size_t)(c) * gstr, (S) + (wave * 4 + ii) * 1024); \
  }

  f32x4 acc0 = {0.f, 0.f, 0.f, 0.f}, acc1 = acc0, accS = acc0;

  auto consume = [&](const unsigned char* base, int c) {
#pragma unroll
    for (int ks = 0; ks < 2; ++ks) {
      int4 A0 = *(const int4*)(base + (rg * 4 + ks * 2 + 0) * 1024 + lane * 16);
      int4 A1 = *(const int4*)(base + (rg * 4 + ks * 2 + 1) * 1024 + lane * 16);
      const float* sp = &s2s[c * 64 + ks * 32 + q * 8];
      float4 sv0 = *(const float4*)sp;
      float4 sv1 = *(const float4*)(sp + 4);
      float xs[8] = {sv0.x, sv0.y, sv0.z, sv0.w, sv1.x, sv1.y, sv1.z, sv1.w};
      int avs[8] = {A0.x, A0.y, A0.z, A0.w, A1.x, A1.y, A1.z, A1.w};
      f16x8 af;
#pragma unroll
      for (int j = 0; j < 8; ++j) {
        float x = xs[j];
        float e = fmaxf(c1 + x, fmaf(LRELU_ALPHA, x, c2));
        e = avs[j] ? e : NEG_INF;
        af[j] = (_Float16)__builtin_amdgcn_exp2f(e);  // masked -> exactly 0
      }
      f16x8 b0 = *(const f16x8*)(base + (8 + (p0 + 0) * 2 + ks) * 1024 + lane * 16);
      f16x8 b1 = *(const f16x8*)(base + (8 + (p0 + 1) * 2 + ks) * 1024 + lane * 16);
      acc0 = __builtin_amdgcn_mfma_f32_16x16x32_f16(af, b0, acc0, 0, 0, 0);
      acc1 = __builtin_amdgcn_mfma_f32_16x16x32_f16(af, b1, acc1, 0, 0, 0);
      accS = __builtin_amdgcn_mfma_f32_16x16x32_f16(af, ones, accS, 0, 0, 0);
    }
  };

  // prologue: 3 chunks staged; full drain once (also publishes s2s)
  STAGE(sbuf[0], 0)
  STAGE(sbuf[1], 1)
  STAGE(sbuf[2], 2)
  __syncthreads();

  consume(sbuf[0], 0);
  STAGE(sbuf[3], 3)

  for (int c = 1; c <= 28; ++c) {
    asm volatile("s_waitcnt vmcnt(8)" ::: "memory");  // chunk c landed (own 4)
    __builtin_amdgcn_s_barrier();                     // => all waves' chunk c
    consume(sbuf[c & 3], c);
    STAGE(sbuf[(c + 3) & 3], c + 3)   // last STAGE: chunk 31 at c=28
  }
  // epilogue: chunks 29 (30,31 in flight), 30 (31 in flight), 31
  asm volatile("s_waitcnt vmcnt(8)" ::: "memory");
  __builtin_amdgcn_s_barrier();
  consume(sbuf[1], 29);
  asm volatile("s_waitcnt vmcnt(4)" ::: "memory");
  __builtin_amdgcn_s_barrier();
  consume(sbuf[2], 30);
  asm volatile("s_waitcnt vmcnt(0)" ::: "memory");
  __builtin_amdgcn_s_barrier();
  consume(sbuf[3], 31);

  // C/D layout: row_in_tile = q*4 + r, col = m; accS[r] = rowsum(q*4+r)
#pragma unroll
  for (int r = 0; r < 4; ++r) {
    const int ri = q * 4 + r;
    const float l = accS[r];
    const float inv = (l == 0.f) ? 1.f : 1.f / l;  // fully-masked row guard
    const size_t row = (size_t)b * N_ + i0 + rg * 16 + ri;
    out[row * FOUT + (p0 + 0) * 16 + m] = acc0[r] * inv;
    out[row * FOUT + (p0 + 1) * 16 + m] = acc1[r] * inv;
  }
#undef STAGE
}

extern "C" void kernel_launch(void* const* d_in, const int* in_sizes, int n_in,
                              void* d_out, int out_size, void* d_ws, size_t ws_size,
                              hipStream_t stream) {
  const float* h   = (const float*)d_in[0];
  const int*   adj = (const int*)d_in[1];
  const float* W   = (const float*)d_in[2];
  const float* a   = (const float*)d_in[3];
  float* out = (float*)d_out;

  // ws: WhT fp16 (2 MB) | s1 (64 KB) | s2 (64 KB)
  unsigned short* WhT = (unsigned short*)d_ws;
  float* s1 = (float*)(WhT + (size_t)B_ * 64 * N_);
  float* s2 = s1 + (size_t)B_ * N_;

  k_wh<<<dim3(B_ * N_ / 16), 256, 0, stream>>>(h, W, a, WhT, s1, s2);
  k_attn<<<dim3(B_, N_ / 32), 256, 0, stream>>>(WhT, s1, s2, adj, out);
}